// Round 1
// baseline (545.677 us; speedup 1.0000x reference)
//
#include <hip/hip_runtime.h>

// Problem constants (from reference)
#define BB 128
#define RR 1024
#define CC 252
#define NSTEPS 232        // C - SCAN_LEN_OFFSET
#define OUTC 484          // 2*NSTEPS + 20
#define NROWS (BB * RR)   // 131072

#define INITIAL_DELTA 0.1f
#define DELTA_LOW 0.02f
#define DELTA_HIGH 0.1f

__global__ __launch_bounds__(256) void DeltaModulator_kernel(
    const float* __restrict__ x, float* __restrict__ out)
{
    const int row = blockIdx.x * blockDim.x + threadIdx.x;
    if (row >= NROWS) return;

    const float* xrow = x + (size_t)row * CC;
    float* orow = out + (size_t)row * OUTC;

    // scan state
    float dc = 0.0f;
    float delta = INITIAL_DELTA;
    float tc = 0.0f;
    float ntc = 0.0f;

    const float4* __restrict__ x4 = reinterpret_cast<const float4*>(xrow);
    float4* __restrict__ up4 = reinterpret_cast<float4*>(orow);           // out[0:232]
    float4* __restrict__ dn4 = reinterpret_cast<float4*>(orow + NSTEPS);  // out[232:464]

    #pragma unroll 2
    for (int i = 0; i < NSTEPS / 4; ++i) {
        float4 xv = x4[i];
        float xs[4] = {xv.x, xv.y, xv.z, xv.w};
        float u[4], d[4];
        #pragma unroll
        for (int j = 0; j < 4; ++j) {
            float xi = xs[j];
            bool up = xi > dc + delta;
            bool dn = xi < dc - delta;
            bool trig = up || dn;
            tc  = trig ? tc + 1.0f : 0.0f;
            ntc = trig ? 0.0f : ntc + 1.0f;
            delta = (tc  >= 3.0f) ? DELTA_LOW  : delta;
            delta = (ntc >= 3.0f) ? DELTA_HIGH : delta;
            dc = trig ? xi : dc;
            u[j] = up ? 1.0f : 0.0f;
            d[j] = dn ? 1.0f : 0.0f;
        }
        up4[i] = make_float4(u[0], u[1], u[2], u[3]);
        dn4[i] = make_float4(d[0], d[1], d[2], d[3]);
    }

    // extra = x[:, :, 232:252] -> out[:, :, 464:484]  (20 floats, 16B aligned)
    const float4* __restrict__ xe = reinterpret_cast<const float4*>(xrow + NSTEPS);
    float4* __restrict__ oe = reinterpret_cast<float4*>(orow + 2 * NSTEPS);
    #pragma unroll
    for (int i = 0; i < 5; ++i) oe[i] = xe[i];
}

extern "C" void kernel_launch(void* const* d_in, const int* in_sizes, int n_in,
                              void* d_out, int out_size, void* d_ws, size_t ws_size,
                              hipStream_t stream) {
    const float* x = (const float*)d_in[0];
    float* out = (float*)d_out;
    const int threads = 256;
    const int blocks = (NROWS + threads - 1) / threads; // 512
    DeltaModulator_kernel<<<blocks, threads, 0, stream>>>(x, out);
}

// Round 2
// 485.250 us; speedup vs baseline: 1.1245x; 1.1245x over previous
//
#include <hip/hip_runtime.h>

// Problem constants (from reference)
#define CC 252
#define NSTEPS 232        // C - SCAN_LEN_OFFSET
#define OUTC 484          // 2*NSTEPS + 20
#define NROWS (128 * 1024)

#define INITIAL_DELTA 0.1f
#define DELTA_LOW 0.02f
#define DELTA_HIGH 0.1f

__device__ __forceinline__ void step4(const float4 xv, float4& uv, float4& dv,
                                      float& dc, float& delta, float& tc, float& ntc)
{
    float xs[4] = {xv.x, xv.y, xv.z, xv.w};
    float u[4], d[4];
    #pragma unroll
    for (int j = 0; j < 4; ++j) {
        float xi = xs[j];
        bool up = xi > dc + delta;
        bool dn = xi < dc - delta;
        bool trig = up || dn;
        tc  = trig ? tc + 1.0f : 0.0f;
        ntc = trig ? 0.0f : ntc + 1.0f;
        delta = (tc  >= 3.0f) ? DELTA_LOW  : delta;
        delta = (ntc >= 3.0f) ? DELTA_HIGH : delta;
        dc = trig ? xi : dc;
        u[j] = up ? 1.0f : 0.0f;
        d[j] = dn ? 1.0f : 0.0f;
    }
    uv = make_float4(u[0], u[1], u[2], u[3]);
    dv = make_float4(d[0], d[1], d[2], d[3]);
}

__global__ __launch_bounds__(256) void DeltaModulator_kernel(
    const float* __restrict__ x, float* __restrict__ out)
{
    const int row = blockIdx.x * blockDim.x + threadIdx.x;
    if (row >= NROWS) return;

    const float* xrow = x + (size_t)row * CC;
    float* orow = out + (size_t)row * OUTC;

    const float4* __restrict__ x4 = reinterpret_cast<const float4*>(xrow);
    float4* __restrict__ up4 = reinterpret_cast<float4*>(orow);           // out[0:232]
    float4* __restrict__ dn4 = reinterpret_cast<float4*>(orow + NSTEPS);  // out[232:464]

    float dc = 0.0f;
    float delta = INITIAL_DELTA;
    float tc = 0.0f;
    float ntc = 0.0f;

    // 7 chunks of 32 steps (8 float4) each: 224 steps, then an 8-step tail.
    // Loads and stores for each chunk are issued back-to-back so each 64B
    // cache line is fully produced/consumed within a short window.
    #pragma unroll 1
    for (int ch = 0; ch < 7; ++ch) {
        const int base = ch * 8;
        float4 xv[8];
        #pragma unroll
        for (int k = 0; k < 8; ++k) xv[k] = x4[base + k];

        float4 uv[8], dv[8];
        #pragma unroll
        for (int k = 0; k < 8; ++k) step4(xv[k], uv[k], dv[k], dc, delta, tc, ntc);

        #pragma unroll
        for (int k = 0; k < 8; ++k) up4[base + k] = uv[k];
        #pragma unroll
        for (int k = 0; k < 8; ++k) dn4[base + k] = dv[k];
    }

    // Tail: steps 224..231 (2 float4)
    {
        float4 xv[2], uv[2], dv[2];
        #pragma unroll
        for (int k = 0; k < 2; ++k) xv[k] = x4[56 + k];
        #pragma unroll
        for (int k = 0; k < 2; ++k) step4(xv[k], uv[k], dv[k], dc, delta, tc, ntc);
        #pragma unroll
        for (int k = 0; k < 2; ++k) up4[56 + k] = uv[k];
        #pragma unroll
        for (int k = 0; k < 2; ++k) dn4[56 + k] = dv[k];
    }

    // extra = x[:, :, 232:252] -> out[:, :, 464:484] (20 floats)
    const float4* __restrict__ xe = reinterpret_cast<const float4*>(xrow + NSTEPS);
    float4* __restrict__ oe = reinterpret_cast<float4*>(orow + 2 * NSTEPS);
    float4 ev[5];
    #pragma unroll
    for (int i = 0; i < 5; ++i) ev[i] = xe[i];
    #pragma unroll
    for (int i = 0; i < 5; ++i) oe[i] = ev[i];
}

extern "C" void kernel_launch(void* const* d_in, const int* in_sizes, int n_in,
                              void* d_out, int out_size, void* d_ws, size_t ws_size,
                              hipStream_t stream) {
    const float* x = (const float*)d_in[0];
    float* out = (float*)d_out;
    const int threads = 256;
    const int blocks = (NROWS + threads - 1) / threads; // 512
    DeltaModulator_kernel<<<blocks, threads, 0, stream>>>(x, out);
}

// Round 3
// 445.232 us; speedup vs baseline: 1.2256x; 1.0899x over previous
//
#include <hip/hip_runtime.h>

// Problem constants (from reference)
#define CC 252
#define NSTEPS 232        // C - SCAN_LEN_OFFSET
#define OUTC 484          // 2*NSTEPS + 20
#define NROWS (128 * 1024)

#define INITIAL_DELTA 0.1f
#define DELTA_LOW 0.02f
#define DELTA_HIGH 0.1f

// One scan step; returns up/dn as bits to OR into the pack words.
__device__ __forceinline__ void step1(float xi, unsigned& upbit, unsigned& dnbit,
                                      float& dc, float& delta, float& tc, float& ntc)
{
    bool up = xi > dc + delta;
    bool dn = xi < dc - delta;
    bool trig = up || dn;
    tc  = trig ? tc + 1.0f : 0.0f;
    ntc = trig ? 0.0f : ntc + 1.0f;
    delta = (tc  >= 3.0f) ? DELTA_LOW  : delta;
    delta = (ntc >= 3.0f) ? DELTA_HIGH : delta;
    dc = trig ? xi : dc;
    upbit = up ? 1u : 0u;
    dnbit = dn ? 1u : 0u;
}

// Extract bit b (compile-time constant after unroll) as 1.0f/0.0f
__device__ __forceinline__ float bitf(const unsigned* w, int b)
{
    return ((w[b >> 5] >> (b & 31)) & 1u) ? 1.0f : 0.0f;
}

__global__ __launch_bounds__(256) void DeltaModulator_kernel(
    const float* __restrict__ x, float* __restrict__ out)
{
    const int row = blockIdx.x * blockDim.x + threadIdx.x;
    if (row >= NROWS) return;

    const float* xrow = x + (size_t)row * CC;
    const float4* __restrict__ x4 = reinterpret_cast<const float4*>(xrow);

    float dc = 0.0f, delta = INITIAL_DELTA, tc = 0.0f, ntc = 0.0f;

    unsigned up_w[8], dn_w[8];   // 232 bits each, fully register-resident

    // ---- Scan phase: 7 chunks of 32 steps (8 float4 loads each) ----
    #pragma unroll
    for (int ch = 0; ch < 7; ++ch) {
        float4 xv[8];
        #pragma unroll
        for (int k = 0; k < 8; ++k) xv[k] = x4[ch * 8 + k];
        unsigned uw = 0u, dw = 0u;
        #pragma unroll
        for (int k = 0; k < 8; ++k) {
            float xs[4] = {xv[k].x, xv[k].y, xv[k].z, xv[k].w};
            #pragma unroll
            for (int j = 0; j < 4; ++j) {
                unsigned ub, db;
                step1(xs[j], ub, db, dc, delta, tc, ntc);
                uw |= ub << (k * 4 + j);
                dw |= db << (k * 4 + j);
            }
        }
        up_w[ch] = uw;
        dn_w[ch] = dw;
    }
    // Tail: steps 224..231 (2 float4) -> word 7, bits 0..7
    {
        float4 xv[2];
        #pragma unroll
        for (int k = 0; k < 2; ++k) xv[k] = x4[56 + k];
        unsigned uw = 0u, dw = 0u;
        #pragma unroll
        for (int k = 0; k < 2; ++k) {
            float xs[4] = {xv[k].x, xv[k].y, xv[k].z, xv[k].w};
            #pragma unroll
            for (int j = 0; j < 4; ++j) {
                unsigned ub, db;
                step1(xs[j], ub, db, dc, delta, tc, ntc);
                uw |= ub << (k * 4 + j);
                dw |= db << (k * 4 + j);
            }
        }
        up_w[7] = uw;
        dn_w[7] = dw;
    }

    // extra = x[:, :, 232:252] held in registers
    const float4* __restrict__ xe = reinterpret_cast<const float4*>(xrow + NSTEPS);
    float4 ev[5];
    #pragma unroll
    for (int i = 0; i < 5; ++i) ev[i] = xe[i];

    // ---- Write phase: entire 1936B row as 121 back-to-back float4 stores ----
    float4* __restrict__ o4 = reinterpret_cast<float4*>(out + (size_t)row * OUTC);

    #pragma unroll
    for (int f = 0; f < 58; ++f) {
        const int b = 4 * f;
        o4[f] = make_float4(bitf(up_w, b), bitf(up_w, b + 1),
                            bitf(up_w, b + 2), bitf(up_w, b + 3));
    }
    #pragma unroll
    for (int f = 0; f < 58; ++f) {
        const int b = 4 * f;
        o4[58 + f] = make_float4(bitf(dn_w, b), bitf(dn_w, b + 1),
                                 bitf(dn_w, b + 2), bitf(dn_w, b + 3));
    }
    #pragma unroll
    for (int i = 0; i < 5; ++i) o4[116 + i] = ev[i];
}

extern "C" void kernel_launch(void* const* d_in, const int* in_sizes, int n_in,
                              void* d_out, int out_size, void* d_ws, size_t ws_size,
                              hipStream_t stream) {
    const float* x = (const float*)d_in[0];
    float* out = (float*)d_out;
    const int threads = 256;
    const int blocks = (NROWS + threads - 1) / threads; // 512
    DeltaModulator_kernel<<<blocks, threads, 0, stream>>>(x, out);
}

// Round 5
// 359.235 us; speedup vs baseline: 1.5190x; 1.2394x over previous
//
#include <hip/hip_runtime.h>

// Problem constants (from reference)
#define CC 252
#define NSTEPS 232        // C - SCAN_LEN_OFFSET
#define OUTC 484          // 2*NSTEPS + 20
#define NROWS (128 * 1024)
#define ROWS_PER_BLOCK 256

#define INITIAL_DELTA 0.1f
#define DELTA_LOW 0.02f
#define DELTA_HIGH 0.1f

#define BITS_STRIDE 17    // u32 per row in LDS (16 words + 1 pad -> odd stride, conflict-free)
#define EXTRA_STRIDE 21   // floats per row in LDS (20 + 1 pad)

__global__ __launch_bounds__(256) void DeltaModulator_kernel(
    const float* __restrict__ x, float* __restrict__ out)
{
    __shared__ unsigned bits_lds[ROWS_PER_BLOCK * BITS_STRIDE];   // 17408 B
    __shared__ float    extra_lds[ROWS_PER_BLOCK * EXTRA_STRIDE]; // 21504 B

    const int t = threadIdx.x;
    const int row0 = blockIdx.x * ROWS_PER_BLOCK;

    // ================= Phase A: per-thread scan of one row =================
    {
        const int row = row0 + t;
        const float* xrow = x + (size_t)row * CC;
        const float4* __restrict__ x4 = reinterpret_cast<const float4*>(xrow);

        float dc = 0.0f, delta = INITIAL_DELTA, tc = 0.0f, ntc = 0.0f;
        unsigned* __restrict__ myb = &bits_lds[t * BITS_STRIDE];

        // 7 chunks of 32 steps (8 float4 each)
        #pragma unroll
        for (int ch = 0; ch < 7; ++ch) {
            float4 xv[8];
            #pragma unroll
            for (int k = 0; k < 8; ++k) xv[k] = x4[ch * 8 + k];
            unsigned uw = 0u, dw = 0u;
            #pragma unroll
            for (int k = 0; k < 8; ++k) {
                float xs[4] = {xv[k].x, xv[k].y, xv[k].z, xv[k].w};
                #pragma unroll
                for (int j = 0; j < 4; ++j) {
                    float xi = xs[j];
                    bool up = xi > dc + delta;
                    bool dn = xi < dc - delta;
                    bool trig = up || dn;
                    tc  = trig ? tc + 1.0f : 0.0f;
                    ntc = trig ? 0.0f : ntc + 1.0f;
                    delta = (tc  >= 3.0f) ? DELTA_LOW  : delta;
                    delta = (ntc >= 3.0f) ? DELTA_HIGH : delta;
                    dc = trig ? xi : dc;
                    uw |= (up ? 1u : 0u) << (k * 4 + j);
                    dw |= (dn ? 1u : 0u) << (k * 4 + j);
                }
            }
            myb[ch]     = uw;   // UP words 0..6
            myb[8 + ch] = dw;   // DN words 8..14
        }
        // Tail: steps 224..231 (2 float4) -> word 7 / 15
        {
            float4 xv[2];
            #pragma unroll
            for (int k = 0; k < 2; ++k) xv[k] = x4[56 + k];
            unsigned uw = 0u, dw = 0u;
            #pragma unroll
            for (int k = 0; k < 2; ++k) {
                float xs[4] = {xv[k].x, xv[k].y, xv[k].z, xv[k].w};
                #pragma unroll
                for (int j = 0; j < 4; ++j) {
                    float xi = xs[j];
                    bool up = xi > dc + delta;
                    bool dn = xi < dc - delta;
                    bool trig = up || dn;
                    tc  = trig ? tc + 1.0f : 0.0f;
                    ntc = trig ? 0.0f : ntc + 1.0f;
                    delta = (tc  >= 3.0f) ? DELTA_LOW  : delta;
                    delta = (ntc >= 3.0f) ? DELTA_HIGH : delta;
                    dc = trig ? xi : dc;
                    uw |= (up ? 1u : 0u) << (k * 4 + j);
                    dw |= (dn ? 1u : 0u) << (k * 4 + j);
                }
            }
            myb[7]  = uw;
            myb[15] = dw;
        }
        // extra = x[row, 232:252] -> LDS
        {
            const float4* __restrict__ xe = reinterpret_cast<const float4*>(xrow + NSTEPS);
            float* __restrict__ mye = &extra_lds[t * EXTRA_STRIDE];
            #pragma unroll
            for (int i = 0; i < 5; ++i) {
                float4 v = xe[i];
                mye[i * 4 + 0] = v.x;
                mye[i * 4 + 1] = v.y;
                mye[i * 4 + 2] = v.z;
                mye[i * 4 + 3] = v.w;
            }
        }
    }

    __syncthreads();

    // ============ Phase B: wave-coalesced expansion of 256 rows ============
    // Block output region: rows row0..row0+255, each OUTC floats = 121 float4.
    // Global float4 index within region: G = r*121 + f. Thread t handles
    // G = i*256 + t for i = 0..120 (121*256 == 256 rows * 121 float4 exactly).
    float4* __restrict__ o4 = reinterpret_cast<float4*>(out + (size_t)row0 * OUTC);

    int r = (t >= 242) ? 2 : ((t >= 121) ? 1 : 0);
    int f = t - r * 121;

    #pragma unroll 1
    for (int i = 0; i < 121; ++i) {
        float4 v;
        if (f < 116) {
            // UP (f<58) or DN (58<=f<116) expansion
            const int idx   = (f < 58) ? f : f - 58;
            const int wbase = (f < 58) ? 0 : 8;
            const unsigned word = bits_lds[r * BITS_STRIDE + wbase + (idx >> 3)];
            const int s = 4 * (idx & 7);
            v = make_float4((float)((word >> s) & 1u),
                            (float)((word >> (s + 1)) & 1u),
                            (float)((word >> (s + 2)) & 1u),
                            (float)((word >> (s + 3)) & 1u));
        } else {
            const float* e = &extra_lds[r * EXTRA_STRIDE + (f - 116) * 4];
            v = make_float4(e[0], e[1], e[2], e[3]);
        }
        o4[r * 121 + f] = v;

        // advance G by 256: 256 = 2*121 + 14
        f += 14; r += 2;
        if (f >= 121) { f -= 121; r += 1; }
    }
}

extern "C" void kernel_launch(void* const* d_in, const int* in_sizes, int n_in,
                              void* d_out, int out_size, void* d_ws, size_t ws_size,
                              hipStream_t stream) {
    const float* x = (const float*)d_in[0];
    float* out = (float*)d_out;
    const int threads = 256;
    const int blocks = NROWS / ROWS_PER_BLOCK; // 512
    DeltaModulator_kernel<<<blocks, threads, 0, stream>>>(x, out);
}

// Round 6
// 358.175 us; speedup vs baseline: 1.5235x; 1.0030x over previous
//
#include <hip/hip_runtime.h>

// Problem constants (from reference)
#define CC 252
#define NSTEPS 232        // C - SCAN_LEN_OFFSET
#define OUTC 484          // 2*NSTEPS + 20
#define NROWS (128 * 1024)
#define ROWS_PER_BLOCK 256

#define INITIAL_DELTA 0.1f
#define DELTA_LOW 0.02f
#define DELTA_HIGH 0.1f

#define BITS_STRIDE 17    // u32 per row in LDS (16 words + 1 pad -> odd stride, conflict-free)
#define EXTRA_STRIDE 21   // floats per row in LDS (20 + 1 pad)

// Scan NV float4 (4*NV steps), packing up/dn bits into uw/dw.
template<int NV>
__device__ __forceinline__ void scan_vecs(const float4* xv, unsigned& uw, unsigned& dw,
                                          float& dc, float& delta, float& tc, float& ntc)
{
    uw = 0u; dw = 0u;
    #pragma unroll
    for (int k = 0; k < NV; ++k) {
        float xs[4] = {xv[k].x, xv[k].y, xv[k].z, xv[k].w};
        #pragma unroll
        for (int j = 0; j < 4; ++j) {
            float xi = xs[j];
            bool up = xi > dc + delta;
            bool dn = xi < dc - delta;
            bool trig = up || dn;
            tc  = trig ? tc + 1.0f : 0.0f;
            ntc = trig ? 0.0f : ntc + 1.0f;
            delta = (tc  >= 3.0f) ? DELTA_LOW  : delta;
            delta = (ntc >= 3.0f) ? DELTA_HIGH : delta;
            dc = trig ? xi : dc;
            uw |= (up ? 1u : 0u) << (k * 4 + j);
            dw |= (dn ? 1u : 0u) << (k * 4 + j);
        }
    }
}

#define PREFETCH8(buf, base) { \
    _Pragma("unroll") for (int k = 0; k < 8; ++k) buf[k] = x4[(base) + k]; }

__global__ __launch_bounds__(256) void DeltaModulator_kernel(
    const float* __restrict__ x, float* __restrict__ out)
{
    __shared__ unsigned bits_lds[ROWS_PER_BLOCK * BITS_STRIDE];   // 17408 B
    __shared__ float    extra_lds[ROWS_PER_BLOCK * EXTRA_STRIDE]; // 21504 B

    const int t = threadIdx.x;
    const int row0 = blockIdx.x * ROWS_PER_BLOCK;

    // ================= Phase A: per-thread scan, software-pipelined =========
    {
        const int row = row0 + t;
        const float* xrow = x + (size_t)row * CC;
        const float4* __restrict__ x4 = reinterpret_cast<const float4*>(xrow);

        float dc = 0.0f, delta = INITIAL_DELTA, tc = 0.0f, ntc = 0.0f;
        unsigned* __restrict__ myb = &bits_lds[t * BITS_STRIDE];
        unsigned uw, dw;

        // Row = 63 float4: chunks c0..c6 (8 vec each, 32 steps each = 224),
        // c7 = vecs 56..62 (tail 8 steps + 5 extra vecs).
        // Ping-pong buffers: prefetch chunk k+1 before computing chunk k so
        // 8 loads are always in flight under the dependent scan VALU chain.
        float4 bA[8], bB[8];

        PREFETCH8(bA, 0);                               // c0
        PREFETCH8(bB, 8);                               // c1 in flight
        scan_vecs<8>(bA, uw, dw, dc, delta, tc, ntc);   // compute c0
        myb[0] = uw; myb[8] = dw;

        PREFETCH8(bA, 16);                              // c2 in flight
        scan_vecs<8>(bB, uw, dw, dc, delta, tc, ntc);   // compute c1
        myb[1] = uw; myb[9] = dw;

        PREFETCH8(bB, 24);                              // c3
        scan_vecs<8>(bA, uw, dw, dc, delta, tc, ntc);   // c2
        myb[2] = uw; myb[10] = dw;

        PREFETCH8(bA, 32);                              // c4
        scan_vecs<8>(bB, uw, dw, dc, delta, tc, ntc);   // c3
        myb[3] = uw; myb[11] = dw;

        PREFETCH8(bB, 40);                              // c5
        scan_vecs<8>(bA, uw, dw, dc, delta, tc, ntc);   // c4
        myb[4] = uw; myb[12] = dw;

        PREFETCH8(bA, 48);                              // c6
        scan_vecs<8>(bB, uw, dw, dc, delta, tc, ntc);   // c5
        myb[5] = uw; myb[13] = dw;

        { // c7: vecs 56..62 (7 float4) into bB
            #pragma unroll
            for (int k = 0; k < 7; ++k) bB[k] = x4[56 + k];
        }
        scan_vecs<8>(bA, uw, dw, dc, delta, tc, ntc);   // c6
        myb[6] = uw; myb[14] = dw;

        // Tail: steps 224..231 from bB[0..1]
        scan_vecs<2>(bB, uw, dw, dc, delta, tc, ntc);
        myb[7] = uw; myb[15] = dw;

        // extra = x[row, 232:252] = vecs 58..62 = bB[2..6] -> LDS
        {
            float* __restrict__ mye = &extra_lds[t * EXTRA_STRIDE];
            #pragma unroll
            for (int i = 0; i < 5; ++i) {
                float4 v = bB[2 + i];
                mye[i * 4 + 0] = v.x;
                mye[i * 4 + 1] = v.y;
                mye[i * 4 + 2] = v.z;
                mye[i * 4 + 3] = v.w;
            }
        }
    }

    __syncthreads();

    // ============ Phase B: wave-coalesced expansion of 256 rows ============
    // Block output region: rows row0..row0+255, each OUTC floats = 121 float4.
    // Thread t handles region-flat float4 index G = i*256 + t, i = 0..120
    // (121*256 float4 == exactly 256 rows). G = r*121 + f tracked incrementally.
    float4* __restrict__ o4 = reinterpret_cast<float4*>(out + (size_t)row0 * OUTC);

    int r = (t >= 242) ? 2 : ((t >= 121) ? 1 : 0);
    int f = t - r * 121;

    #pragma unroll 1
    for (int i = 0; i < 121; ++i) {
        float4 v;
        if (f < 116) {
            // UP (f<58) or DN (58<=f<116) expansion
            const int idx   = (f < 58) ? f : f - 58;
            const int wbase = (f < 58) ? 0 : 8;
            const unsigned word = bits_lds[r * BITS_STRIDE + wbase + (idx >> 3)];
            const int s = 4 * (idx & 7);
            v = make_float4((float)((word >> s) & 1u),
                            (float)((word >> (s + 1)) & 1u),
                            (float)((word >> (s + 2)) & 1u),
                            (float)((word >> (s + 3)) & 1u));
        } else {
            const float* e = &extra_lds[r * EXTRA_STRIDE + (f - 116) * 4];
            v = make_float4(e[0], e[1], e[2], e[3]);
        }
        o4[r * 121 + f] = v;

        // advance G by 256: 256 = 2*121 + 14
        f += 14; r += 2;
        if (f >= 121) { f -= 121; r += 1; }
    }
}

extern "C" void kernel_launch(void* const* d_in, const int* in_sizes, int n_in,
                              void* d_out, int out_size, void* d_ws, size_t ws_size,
                              hipStream_t stream) {
    const float* x = (const float*)d_in[0];
    float* out = (float*)d_out;
    const int threads = 256;
    const int blocks = NROWS / ROWS_PER_BLOCK; // 512
    DeltaModulator_kernel<<<blocks, threads, 0, stream>>>(x, out);
}